// Round 1
// baseline (59.087 us; speedup 1.0000x reference)
//
#include <hip/hip_runtime.h>

// MTRNN single step. Live computation after DCE (reference returns only y):
//   io_new = tanh(0.5*io_state + 0.5*([x|io|cf] @ [Wi2io|Wio2io|Wcf2io]^T + bsum))
//   y      = tanh(io_new @ Wio2o^T + bio2o)
// cf_new / cs_new never feed y -> not computed.
// All GEMMs in bf16 MFMA (f32 accumulate); validated threshold is 1.3e-2.

typedef float f32x4 __attribute__((ext_vector_type(4)));
typedef __bf16 bf16x8 __attribute__((ext_vector_type(8)));
typedef unsigned short u16x8 __attribute__((ext_vector_type(8)));
typedef unsigned short u16x4 __attribute__((ext_vector_type(4)));

// f32 -> bf16 round-to-nearest-even
__device__ __forceinline__ unsigned short f2bf(float f) {
    unsigned u = __builtin_bit_cast(unsigned, f);
    u += 0x7FFFu + ((u >> 16) & 1u);
    return (unsigned short)(u >> 16);
}

// XOR swizzle for a [rows][64] bf16 tile (row stride 128 B): kills the
// 128B-stride bank conflict on ds_read_b128 (Guideline 4).
__device__ __forceinline__ int swz(int row, int kbyte) {
    return ((row << 7) + kbyte) ^ ((row & 7) << 4);
}

// ---------------------------------------------------------------------------
// Kernel 0: pack live weights to bf16 in workspace.
//   wcat[512][1152] = [Wi2io(128) | Wio2io(512) | Wcf2io(512)] per row
//   w2  [128][512]  = Wio2o
// ---------------------------------------------------------------------------
__global__ __launch_bounds__(256) void k_convert(
    const float* __restrict__ Wi2io, const float* __restrict__ Wio2io,
    const float* __restrict__ Wcf2io, const float* __restrict__ Wio2o,
    unsigned short* __restrict__ wcat, unsigned short* __restrict__ w2)
{
    int idx = blockIdx.x * 256 + threadIdx.x;
    if (idx < 147456) {              // 512*1152/4 quads
        int n = idx / 288;
        int k = (idx - n * 288) * 4;
        const float* s;
        if (k < 128)      s = Wi2io  + n * 128 + k;
        else if (k < 640) s = Wio2io + n * 512 + (k - 128);
        else              s = Wcf2io + n * 512 + (k - 640);
        f32x4 v = *(const f32x4*)s;
        u16x4 h; h[0]=f2bf(v[0]); h[1]=f2bf(v[1]); h[2]=f2bf(v[2]); h[3]=f2bf(v[3]);
        *(u16x4*)(wcat + n * 1152 + k) = h;
    } else if (idx < 163840) {       // + 128*512/4 quads
        int q = idx - 147456;
        int n = q >> 7;
        int k = (q & 127) * 4;
        f32x4 v = *(const f32x4*)(Wio2o + n * 512 + k);
        u16x4 h; h[0]=f2bf(v[0]); h[1]=f2bf(v[1]); h[2]=f2bf(v[2]); h[3]=f2bf(v[3]);
        *(u16x4*)(w2 + n * 512 + k) = h;
    }
}

// ---------------------------------------------------------------------------
// Kernel 1: io_new = tanh(0.5*io + 0.5*(Acat @ Wcat^T + bsum)), bf16 out.
// M=8192 N=512 K=1152. Tile 128x128, BK=64, 512 threads (8 waves, 2x4),
// wave tile 64x32. Reg-staged LDS with f32->bf16 convert for A.
// ---------------------------------------------------------------------------
__global__ __launch_bounds__(512, 2) void k_gemm1(
    const float* __restrict__ x, const float* __restrict__ io,
    const float* __restrict__ cf,
    const unsigned short* __restrict__ wcat,
    const float* __restrict__ b_i2io, const float* __restrict__ b_io2io,
    const float* __restrict__ b_cf2io,
    unsigned short* __restrict__ ionew)
{
    __shared__ __align__(16) char ldsA[128 * 64 * 2];
    __shared__ __align__(16) char ldsB[128 * 64 * 2];

    const int tid  = threadIdx.x;
    const int m0   = (blockIdx.x >> 2) << 7;   // 64 row blocks
    const int n0   = (blockIdx.x & 3) << 7;    // 4 col blocks
    const int lane = tid & 63;
    const int wid  = tid >> 6;
    const int wm   = (wid >> 2) * 64;
    const int wn   = (wid & 3) * 32;
    const int lrow = lane & 15;
    const int lk   = (lane >> 4) * 8;          // k element offset of this lane

    f32x4 acc[4][2];
    f32x4 z = {0.f, 0.f, 0.f, 0.f};
    #pragma unroll
    for (int i = 0; i < 4; ++i)
        #pragma unroll
        for (int j = 0; j < 2; ++j) acc[i][j] = z;

    for (int kt = 0; kt < 18; ++kt) {
        const float* src; int stride, col0;
        if (kt < 2)       { src = x;  stride = 128; col0 = kt * 64; }
        else if (kt < 10) { src = io; stride = 512; col0 = (kt - 2) * 64; }
        else              { src = cf; stride = 512; col0 = (kt - 10) * 64; }

        __syncthreads();
        // stage A: 128 rows x 64 f32 -> bf16, 2048 float4 quads / 512 thr
        #pragma unroll
        for (int j = 0; j < 4; ++j) {
            int q   = tid + 512 * j;
            int row = q >> 4;
            int c4  = (q & 15) * 4;
            f32x4 v = *(const f32x4*)(src + (size_t)(m0 + row) * stride + col0 + c4);
            u16x4 h; h[0]=f2bf(v[0]); h[1]=f2bf(v[1]); h[2]=f2bf(v[2]); h[3]=f2bf(v[3]);
            *(u16x4*)(ldsA + swz(row, c4 * 2)) = h;
        }
        // stage B: 128 rows x 64 bf16 (already bf16), 1024 x 16B / 512 thr
        const unsigned short* wsrc = wcat + kt * 64;
        #pragma unroll
        for (int j = 0; j < 2; ++j) {
            int q   = tid + 512 * j;
            int row = q >> 3;
            int c8  = (q & 7) * 8;
            u16x8 wv = *(const u16x8*)(wsrc + (size_t)(n0 + row) * 1152 + c8);
            *(u16x8*)(ldsB + swz(row, c8 * 2)) = wv;
        }
        __syncthreads();

        #pragma unroll
        for (int ks = 0; ks < 2; ++ks) {
            int kb = (ks * 32 + lk) * 2;
            bf16x8 a[4], b[2];
            #pragma unroll
            for (int mi = 0; mi < 4; ++mi) {
                int r = wm + mi * 16 + lrow;
                a[mi] = *(const bf16x8*)(ldsA + swz(r, kb));
            }
            #pragma unroll
            for (int nj = 0; nj < 2; ++nj) {
                int r = wn + nj * 16 + lrow;
                b[nj] = *(const bf16x8*)(ldsB + swz(r, kb));
            }
            #pragma unroll
            for (int mi = 0; mi < 4; ++mi)
                #pragma unroll
                for (int nj = 0; nj < 2; ++nj)
                    acc[mi][nj] = __builtin_amdgcn_mfma_f32_16x16x32_bf16(
                        a[mi], b[nj], acc[mi][nj], 0, 0, 0);
        }
    }

    // epilogue: leaky integrate + tanh, write bf16 io_new
    #pragma unroll
    for (int nj = 0; nj < 2; ++nj) {
        int gn = n0 + wn + nj * 16 + lrow;
        float bsum = b_i2io[gn] + b_io2io[gn] + b_cf2io[gn];
        #pragma unroll
        for (int mi = 0; mi < 4; ++mi) {
            #pragma unroll
            for (int r = 0; r < 4; ++r) {
                int gm  = m0 + wm + mi * 16 + (lane >> 4) * 4 + r;
                float s = acc[mi][nj][r];
                float v = tanhf(0.5f * io[(size_t)gm * 512 + gn] + 0.5f * (s + bsum));
                ionew[(size_t)gm * 512 + gn] = f2bf(v);
            }
        }
    }
}

// ---------------------------------------------------------------------------
// Kernel 2: y = tanh(io_new @ Wio2o^T + bio2o). M=8192 N=128 K=512.
// Tile 32x128 (full N), BK=64, 256 threads (4 waves, 2x2), wave tile 16x64.
// ---------------------------------------------------------------------------
__global__ __launch_bounds__(256, 2) void k_gemm2(
    const unsigned short* __restrict__ ionew,
    const unsigned short* __restrict__ w2,
    const float* __restrict__ b_io2o,
    float* __restrict__ out)
{
    __shared__ __align__(16) char ldsA[32 * 64 * 2];
    __shared__ __align__(16) char ldsB[128 * 64 * 2];

    const int tid  = threadIdx.x;
    const int m0   = blockIdx.x << 5;
    const int lane = tid & 63;
    const int wid  = tid >> 6;
    const int wm   = (wid >> 1) * 16;
    const int wn   = (wid & 1) * 64;
    const int lrow = lane & 15;
    const int lk   = (lane >> 4) * 8;

    f32x4 acc[4];
    f32x4 z = {0.f, 0.f, 0.f, 0.f};
    #pragma unroll
    for (int j = 0; j < 4; ++j) acc[j] = z;

    for (int kt = 0; kt < 8; ++kt) {
        __syncthreads();
        {   // stage A: 32 rows x 64 bf16 = 256 x 16B chunks, 1/thread
            int row = tid >> 3;
            int c8  = (tid & 7) * 8;
            u16x8 v = *(const u16x8*)(ionew + (size_t)(m0 + row) * 512 + kt * 64 + c8);
            *(u16x8*)(ldsA + swz(row, c8 * 2)) = v;
        }
        #pragma unroll
        for (int j = 0; j < 4; ++j) {   // stage B: 128 rows x 64 bf16
            int q   = tid + 256 * j;
            int row = q >> 3;
            int c8  = (q & 7) * 8;
            u16x8 v = *(const u16x8*)(w2 + (size_t)row * 512 + kt * 64 + c8);
            *(u16x8*)(ldsB + swz(row, c8 * 2)) = v;
        }
        __syncthreads();

        #pragma unroll
        for (int ks = 0; ks < 2; ++ks) {
            int kb = (ks * 32 + lk) * 2;
            bf16x8 a = *(const bf16x8*)(ldsA + swz(wm + lrow, kb));
            #pragma unroll
            for (int nj = 0; nj < 4; ++nj) {
                bf16x8 b = *(const bf16x8*)(ldsB + swz(wn + nj * 16 + lrow, kb));
                acc[nj] = __builtin_amdgcn_mfma_f32_16x16x32_bf16(a, b, acc[nj], 0, 0, 0);
            }
        }
    }

    #pragma unroll
    for (int nj = 0; nj < 4; ++nj) {
        int col  = wn + nj * 16 + lrow;
        float bb = b_io2o[col];
        #pragma unroll
        for (int r = 0; r < 4; ++r) {
            int gm = m0 + wm + (lane >> 4) * 4 + r;
            out[(size_t)gm * 128 + col] = tanhf(acc[nj][r] + bb);
        }
    }
}

// ---------------------------------------------------------------------------
extern "C" void kernel_launch(void* const* d_in, const int* in_sizes, int n_in,
                              void* d_out, int out_size, void* d_ws, size_t ws_size,
                              hipStream_t stream)
{
    const float* x      = (const float*)d_in[0];
    const float* io     = (const float*)d_in[1];
    const float* cf     = (const float*)d_in[2];
    // d_in[3] cs_state: dead (does not feed y)
    const float* Wi2io  = (const float*)d_in[4];
    const float* bi2io  = (const float*)d_in[5];
    const float* Wio2o  = (const float*)d_in[6];
    const float* bio2o  = (const float*)d_in[7];
    const float* Wio2io = (const float*)d_in[8];
    const float* bio2io = (const float*)d_in[9];
    const float* Wcf2io = (const float*)d_in[12];
    const float* bcf2io = (const float*)d_in[13];
    float* out = (float*)d_out;

    // workspace layout (bytes): wcat 1,179,648 | w2 131,072 | ionew 8,388,608
    char* ws = (char*)d_ws;
    unsigned short* wcat  = (unsigned short*)ws;
    unsigned short* w2    = (unsigned short*)(ws + 1179648);
    unsigned short* ionew = (unsigned short*)(ws + 1310720);

    hipLaunchKernelGGL(k_convert, dim3(640), dim3(256), 0, stream,
                       Wi2io, Wio2io, Wcf2io, Wio2o, wcat, w2);
    hipLaunchKernelGGL(k_gemm1, dim3(256), dim3(512), 0, stream,
                       x, io, cf, wcat, bi2io, bio2io, bcf2io, ionew);
    hipLaunchKernelGGL(k_gemm2, dim3(256), dim3(256), 0, stream,
                       ionew, w2, bio2o, out);
}

// Round 2
// 39.465 us; speedup vs baseline: 1.4972x; 1.4972x over previous
//
#include <hip/hip_runtime.h>

// MTRNN single step. Live computation after DCE (reference returns only y):
//   io_new = tanh([x|io|cf] @ (0.5*[Wi2io | Wio2io+I | Wcf2io])^T + 0.5*bsum)
//   y      = tanh(io_new @ Wio2o^T + bio2o)
// (0.5*io_state folded into the weight matrix via +I on the io2io block.)
// cf_new / cs_new are dead code. bf16 MFMA, f32 accumulate.

typedef float f32x4 __attribute__((ext_vector_type(4)));
typedef __bf16 bf16x8 __attribute__((ext_vector_type(8)));
typedef unsigned short u16x8 __attribute__((ext_vector_type(8)));
typedef unsigned short u16x4 __attribute__((ext_vector_type(4)));

// f32 -> bf16 round-to-nearest-even
__device__ __forceinline__ unsigned short f2bf(float f) {
    unsigned u = __builtin_bit_cast(unsigned, f);
    u += 0x7FFFu + ((u >> 16) & 1u);
    return (unsigned short)(u >> 16);
}

// XOR swizzle for [rows][64] bf16 tiles (row stride 128 B): kills the
// 128B-stride bank conflict on ds_read_b128 (Guideline 4, T2).
__device__ __forceinline__ int swz(int row, int kbyte) {
    return ((row << 7) + kbyte) ^ ((row & 7) << 4);
}

// ---------------------------------------------------------------------------
// Kernel 0: pack live weights to bf16.
//   wcat[512][1152] = 0.5*[Wi2io | Wio2io + I | Wcf2io]   (leaky-int folded)
//   w2  [128][512]  = Wio2o
// ---------------------------------------------------------------------------
__global__ __launch_bounds__(256) void k_convert(
    const float* __restrict__ Wi2io, const float* __restrict__ Wio2io,
    const float* __restrict__ Wcf2io, const float* __restrict__ Wio2o,
    unsigned short* __restrict__ wcat, unsigned short* __restrict__ w2)
{
    int idx = blockIdx.x * 256 + threadIdx.x;
    if (idx < 147456) {              // 512*1152/4 quads
        int n = idx / 288;
        int k = (idx - n * 288) * 4;
        const float* s;
        if (k < 128)      s = Wi2io  + n * 128 + k;
        else if (k < 640) s = Wio2io + n * 512 + (k - 128);
        else              s = Wcf2io + n * 512 + (k - 640);
        f32x4 v = *(const f32x4*)s;
        u16x4 h;
        #pragma unroll
        for (int t = 0; t < 4; ++t) {
            float f = 0.5f * v[t];
            int kk = k + t;
            if (kk >= 128 && kk < 640 && (kk - 128) == n) f += 0.5f;  // +0.5*I
            h[t] = f2bf(f);
        }
        *(u16x4*)(wcat + n * 1152 + k) = h;
    } else if (idx < 163840) {       // + 128*512/4 quads
        int q = idx - 147456;
        int n = q >> 7;
        int k = (q & 127) * 4;
        f32x4 v = *(const f32x4*)(Wio2o + n * 512 + k);
        u16x4 h; h[0]=f2bf(v[0]); h[1]=f2bf(v[1]); h[2]=f2bf(v[2]); h[3]=f2bf(v[3]);
        *(u16x4*)(w2 + n * 512 + k) = h;
    }
}

// ---------------------------------------------------------------------------
// Kernel 1: ionew = tanh(Acat @ wcat^T + 0.5*bsum), bf16 out.
// M=8192 N=512 K=1152. Tile 64x128, BK=64, 256 thr (4 waves, 2x2, wave 32x64).
// Grid 512 -> 2 blocks/CU. Double-buffered LDS, issue-early/write-late
// reg staging (f32->bf16 convert in flight for A). XCD swizzle: the 4
// col-blocks of each 64-row A panel land on one XCD (L2 reuse).
// ---------------------------------------------------------------------------
__global__ __launch_bounds__(256, 2) void k_gemm1(
    const float* __restrict__ x, const float* __restrict__ io,
    const float* __restrict__ cf,
    const unsigned short* __restrict__ wcat,
    const float* __restrict__ b1, const float* __restrict__ b2,
    const float* __restrict__ b3,
    unsigned short* __restrict__ ionew)
{
    // per buffer: A 64x64 bf16 (8 KB) @0, B 128x64 bf16 (16 KB) @8192
    __shared__ __align__(16) char lds[2][24576];

    const int tid = threadIdx.x;
    const int b   = blockIdx.x;
    // b%8 -> XCD; give XCD x row panels {x, x+8, ...}, 4 col-blocks each.
    const int row_blk = (b & 7) + ((b >> 5) << 3);   // 0..127
    const int col_blk = (b >> 3) & 3;                // 0..3
    const int m0 = row_blk << 6;
    const int n0 = col_blk << 7;

    const int lane = tid & 63;
    const int wid  = tid >> 6;
    const int wm   = (wid >> 1) << 5;     // 0 / 32
    const int wn   = (wid & 1) << 6;      // 0 / 64
    const int lrow = lane & 15;
    const int lk2  = (lane >> 4) << 4;    // k byte offset within 128B row

    f32x4 ra[4]; u16x8 rb[4];
    f32x4 acc[2][4];
    f32x4 z = {0.f, 0.f, 0.f, 0.f};
    #pragma unroll
    for (int i = 0; i < 2; ++i)
        #pragma unroll
        for (int j = 0; j < 4; ++j) acc[i][j] = z;

#define ISSUE1(KT) do {                                                        \
        int K_ = (KT);                                                         \
        const float* sp; int st, c0;                                           \
        if (K_ < 2)       { sp = x;  st = 128; c0 = K_ << 6; }                 \
        else if (K_ < 10) { sp = io; st = 512; c0 = (K_ - 2) << 6; }           \
        else              { sp = cf; st = 512; c0 = (K_ - 10) << 6; }          \
        _Pragma("unroll")                                                      \
        for (int j = 0; j < 4; ++j) {                                          \
            int q = tid + 256 * j;                                             \
            ra[j] = *(const f32x4*)(sp + (size_t)(m0 + (q >> 4)) * st          \
                                       + c0 + ((q & 15) << 2));                \
        }                                                                      \
        const unsigned short* wp = wcat + (K_ << 6);                           \
        _Pragma("unroll")                                                      \
        for (int j = 0; j < 4; ++j) {                                          \
            int q = tid + 256 * j;                                             \
            rb[j] = *(const u16x8*)(wp + (size_t)(n0 + (q >> 3)) * 1152        \
                                       + ((q & 7) << 3));                      \
        }                                                                      \
    } while (0)

#define WRITE1(BUF) do {                                                       \
        char* A_ = (BUF); char* B_ = (BUF) + 8192;                             \
        _Pragma("unroll")                                                      \
        for (int j = 0; j < 4; ++j) {                                          \
            int q = tid + 256 * j;                                             \
            u16x4 h;                                                           \
            h[0] = f2bf(ra[j][0]); h[1] = f2bf(ra[j][1]);                      \
            h[2] = f2bf(ra[j][2]); h[3] = f2bf(ra[j][3]);                      \
            *(u16x4*)(A_ + swz(q >> 4, (q & 15) << 3)) = h;                    \
            *(u16x8*)(B_ + swz(q >> 3, (q & 7) << 4)) = rb[j];                 \
        }                                                                      \
    } while (0)

#define COMPUTE1(BUF) do {                                                     \
        const char* A_ = (BUF); const char* B_ = (BUF) + 8192;                 \
        _Pragma("unroll")                                                      \
        for (int ks = 0; ks < 2; ++ks) {                                       \
            int kb = ks * 64 + lk2;                                            \
            bf16x8 af[2], bfr[4];                                              \
            _Pragma("unroll")                                                  \
            for (int mi = 0; mi < 2; ++mi)                                     \
                af[mi] = *(const bf16x8*)(A_ + swz(wm + mi * 16 + lrow, kb));  \
            _Pragma("unroll")                                                  \
            for (int nj = 0; nj < 4; ++nj)                                     \
                bfr[nj] = *(const bf16x8*)(B_ + swz(wn + nj * 16 + lrow, kb)); \
            _Pragma("unroll")                                                  \
            for (int mi = 0; mi < 2; ++mi)                                     \
                _Pragma("unroll")                                              \
                for (int nj = 0; nj < 4; ++nj)                                 \
                    acc[mi][nj] = __builtin_amdgcn_mfma_f32_16x16x32_bf16(     \
                        af[mi], bfr[nj], acc[mi][nj], 0, 0, 0);                \
        }                                                                      \
    } while (0)

    ISSUE1(0);
    WRITE1(lds[0]);
    __syncthreads();
    int cur = 0;
    for (int kt = 0; kt < 18; ++kt) {
        if (kt < 17) ISSUE1(kt + 1);     // loads in flight across compute
        COMPUTE1(lds[cur]);
        if (kt < 17) WRITE1(lds[cur ^ 1]);
        __syncthreads();
        cur ^= 1;
    }

    // epilogue: bias + tanh (leaky term already folded into wcat)
    #pragma unroll
    for (int nj = 0; nj < 4; ++nj) {
        int gn = n0 + wn + nj * 16 + lrow;
        float bb = 0.5f * (b1[gn] + b2[gn] + b3[gn]);
        #pragma unroll
        for (int mi = 0; mi < 2; ++mi) {
            #pragma unroll
            for (int r = 0; r < 4; ++r) {
                int gm = m0 + wm + mi * 16 + ((lane >> 4) << 2) + r;
                ionew[(size_t)gm * 512 + gn] = f2bf(tanhf(acc[mi][nj][r] + bb));
            }
        }
    }
#undef ISSUE1
#undef WRITE1
#undef COMPUTE1
}

// ---------------------------------------------------------------------------
// Kernel 2: y = tanh(ionew @ w2^T + bio2o). M=8192 N=128 K=512.
// Tile 32x64, BK=64, 128 thr (2 waves, wave 16x64). Grid 512 -> 2 blocks/CU.
// Same dbuf pipeline. Swizzled so reads hit the L2 where gemm1 wrote.
// ---------------------------------------------------------------------------
__global__ __launch_bounds__(128, 2) void k_gemm2(
    const unsigned short* __restrict__ ionew,
    const unsigned short* __restrict__ w2,
    const float* __restrict__ b_io2o,
    float* __restrict__ out)
{
    // per buffer: A 32x64 (4 KB) @0, B 64x64 (8 KB) @4096
    __shared__ __align__(16) char lds[2][12288];

    const int tid = threadIdx.x;
    const int b   = blockIdx.x;
    // row panel r2 -> XCD (r2>>1)%8 == b%8 : matches gemm1's writer XCD.
    const int r2 = 2 * (b & 7) + ((b >> 3) & 1) + ((b >> 5) << 4);  // 0..255
    const int c2 = (b >> 4) & 1;
    const int m0 = r2 << 5;
    const int n0 = c2 << 6;

    const int lane = tid & 63;
    const int wid  = tid >> 6;        // 0..1
    const int wm   = wid << 4;        // 0 / 16
    const int lrow = lane & 15;
    const int lk2  = (lane >> 4) << 4;

    u16x8 ra[2], rb[4];
    f32x4 acc[4];
    f32x4 z = {0.f, 0.f, 0.f, 0.f};
    #pragma unroll
    for (int j = 0; j < 4; ++j) acc[j] = z;

#define ISSUE2(KT) do {                                                        \
        const unsigned short* ap = ionew + ((KT) << 6);                        \
        _Pragma("unroll")                                                      \
        for (int j = 0; j < 2; ++j) {                                          \
            int q = tid + 128 * j;                                             \
            ra[j] = *(const u16x8*)(ap + (size_t)(m0 + (q >> 3)) * 512         \
                                       + ((q & 7) << 3));                      \
        }                                                                      \
        const unsigned short* bp = w2 + ((KT) << 6);                           \
        _Pragma("unroll")                                                      \
        for (int j = 0; j < 4; ++j) {                                          \
            int q = tid + 128 * j;                                             \
            rb[j] = *(const u16x8*)(bp + (size_t)(n0 + (q >> 3)) * 512         \
                                       + ((q & 7) << 3));                      \
        }                                                                      \
    } while (0)

#define WRITE2(BUF) do {                                                       \
        char* A_ = (BUF); char* B_ = (BUF) + 4096;                             \
        _Pragma("unroll")                                                      \
        for (int j = 0; j < 2; ++j) {                                          \
            int q = tid + 128 * j;                                             \
            *(u16x8*)(A_ + swz(q >> 3, (q & 7) << 4)) = ra[j];                 \
        }                                                                      \
        _Pragma("unroll")                                                      \
        for (int j = 0; j < 4; ++j) {                                          \
            int q = tid + 128 * j;                                             \
            *(u16x8*)(B_ + swz(q >> 3, (q & 7) << 4)) = rb[j];                 \
        }                                                                      \
    } while (0)

#define COMPUTE2(BUF) do {                                                     \
        const char* A_ = (BUF); const char* B_ = (BUF) + 4096;                 \
        _Pragma("unroll")                                                      \
        for (int ks = 0; ks < 2; ++ks) {                                       \
            int kb = ks * 64 + lk2;                                            \
            bf16x8 af = *(const bf16x8*)(A_ + swz(wm + lrow, kb));             \
            _Pragma("unroll")                                                  \
            for (int nj = 0; nj < 4; ++nj) {                                   \
                bf16x8 bfr = *(const bf16x8*)(B_ + swz(nj * 16 + lrow, kb));   \
                acc[nj] = __builtin_amdgcn_mfma_f32_16x16x32_bf16(             \
                    af, bfr, acc[nj], 0, 0, 0);                                \
            }                                                                  \
        }                                                                      \
    } while (0)

    ISSUE2(0);
    WRITE2(lds[0]);
    __syncthreads();
    int cur = 0;
    for (int kt = 0; kt < 8; ++kt) {
        if (kt < 7) ISSUE2(kt + 1);
        COMPUTE2(lds[cur]);
        if (kt < 7) WRITE2(lds[cur ^ 1]);
        __syncthreads();
        cur ^= 1;
    }

    #pragma unroll
    for (int nj = 0; nj < 4; ++nj) {
        int col  = n0 + nj * 16 + lrow;
        float bb = b_io2o[col];
        #pragma unroll
        for (int r = 0; r < 4; ++r) {
            int gm = m0 + wm + ((lane >> 4) << 2) + r;
            out[(size_t)gm * 128 + col] = tanhf(acc[nj][r] + bb);
        }
    }
#undef ISSUE2
#undef WRITE2
#undef COMPUTE2
}

// ---------------------------------------------------------------------------
extern "C" void kernel_launch(void* const* d_in, const int* in_sizes, int n_in,
                              void* d_out, int out_size, void* d_ws, size_t ws_size,
                              hipStream_t stream)
{
    const float* x      = (const float*)d_in[0];
    const float* io     = (const float*)d_in[1];
    const float* cf     = (const float*)d_in[2];
    // d_in[3] cs_state: dead (does not feed y)
    const float* Wi2io  = (const float*)d_in[4];
    const float* bi2io  = (const float*)d_in[5];
    const float* Wio2o  = (const float*)d_in[6];
    const float* bio2o  = (const float*)d_in[7];
    const float* Wio2io = (const float*)d_in[8];
    const float* bio2io = (const float*)d_in[9];
    const float* Wcf2io = (const float*)d_in[12];
    const float* bcf2io = (const float*)d_in[13];
    float* out = (float*)d_out;

    // workspace layout (bytes): wcat 1,179,648 | w2 131,072 | ionew 8,388,608
    char* ws = (char*)d_ws;
    unsigned short* wcat  = (unsigned short*)ws;
    unsigned short* w2    = (unsigned short*)(ws + 1179648);
    unsigned short* ionew = (unsigned short*)(ws + 1310720);

    hipLaunchKernelGGL(k_convert, dim3(640), dim3(256), 0, stream,
                       Wi2io, Wio2io, Wcf2io, Wio2o, wcat, w2);
    hipLaunchKernelGGL(k_gemm1, dim3(512), dim3(256), 0, stream,
                       x, io, cf, wcat, bi2io, bio2io, bcf2io, ionew);
    hipLaunchKernelGGL(k_gemm2, dim3(512), dim3(128), 0, stream,
                       ionew, w2, bio2o, out);
}